// Round 1
// baseline (234.731 us; speedup 1.0000x reference)
//
#include <hip/hip_runtime.h>

// LIF forward: x [B=32, T=16, N=65536] f32, thresh scalar f32 -> spikes [B,T,N] f32
//   mem = mem*TAU + x[t];  spike = (mem > thresh);  mem = spike ? 0 : mem;
// Per-(b,n) recurrence over T only -> one fused kernel, mem in registers,
// each input/output byte touched exactly once. Pure HBM-bound: ~268 MB total.

#define TAU 0.25f

__global__ __launch_bounds__(256) void lif_fwd_kernel(
    const float4* __restrict__ x,
    const float* __restrict__ thresh,
    float4* __restrict__ out)
{
    constexpr int T  = 16;
    constexpr int N4 = 65536 / 4;  // 16384 float4 per (b,t) row

    const int gid = blockIdx.x * blockDim.x + threadIdx.x;  // 0 .. B*N4-1
    const int b   = gid >> 14;          // gid / N4
    const int n4  = gid & (N4 - 1);     // gid % N4

    const float th = thresh[0];

    const size_t base = (size_t)b * T * N4 + n4;
    const float4* xp = x   + base;
    float4*       op = out + base;

    float4 mem = make_float4(0.f, 0.f, 0.f, 0.f);

#pragma unroll
    for (int t = 0; t < T; ++t) {
        float4 xt = xp[(size_t)t * N4];

        mem.x = mem.x * TAU + xt.x;
        mem.y = mem.y * TAU + xt.y;
        mem.z = mem.z * TAU + xt.z;
        mem.w = mem.w * TAU + xt.w;

        const bool px = mem.x > th;
        const bool py = mem.y > th;
        const bool pz = mem.z > th;
        const bool pw = mem.w > th;

        float4 s;
        s.x = px ? 1.f : 0.f;
        s.y = py ? 1.f : 0.f;
        s.z = pz ? 1.f : 0.f;
        s.w = pw ? 1.f : 0.f;

        mem.x = px ? 0.f : mem.x;
        mem.y = py ? 0.f : mem.y;
        mem.z = pz ? 0.f : mem.z;
        mem.w = pw ? 0.f : mem.w;

        op[(size_t)t * N4] = s;
    }
}

extern "C" void kernel_launch(void* const* d_in, const int* in_sizes, int n_in,
                              void* d_out, int out_size, void* d_ws, size_t ws_size,
                              hipStream_t stream)
{
    const float* x      = (const float*)d_in[0];
    const float* thresh = (const float*)d_in[1];
    float*       out    = (float*)d_out;

    // total = B*T*N = 33,554,432 ; threads = B*N/4 = total/(T*4) = 524,288
    const int total   = in_sizes[0];
    const int threads = total / (16 * 4);
    const int block   = 256;
    const int grid    = threads / block;   // 2048 blocks

    lif_fwd_kernel<<<grid, block, 0, stream>>>(
        (const float4*)x, thresh, (float4*)out);
}

// Round 3
// 228.542 us; speedup vs baseline: 1.0271x; 1.0271x over previous
//
#include <hip/hip_runtime.h>

// LIF forward: x [B=32, T=16, N=65536] f32, thresh scalar f32 -> spikes [B,T,N] f32
//   mem = mem*TAU + x[t];  spike = (mem > thresh);  mem = spike ? 0 : mem;
//
// R1 was latency-bound (VGPR=20 -> ~2 loads in flight, occupancy 50%, 2.5 TB/s).
// R2: float2/thread, preload ALL 16 t-slices into registers (32 VGPR data,
// ~50 total -> stays under the 64-VGPR cliff => 8 waves/SIMD) giving
// 16 outstanding loads/wave x 8 waves/SIMD. Non-temporal stores keep the
// write stream from evicting warm x out of L2/L3.

#define TAU 0.25f

typedef float f32x2 __attribute__((ext_vector_type(2)));

__global__ __launch_bounds__(256) void lif_fwd_kernel(
    const f32x2* __restrict__ x,
    const float* __restrict__ thresh,
    f32x2* __restrict__ out)
{
    constexpr int T  = 16;
    constexpr int N2 = 65536 / 2;   // 32768 float2 per (b,t) row

    const int gid = blockIdx.x * blockDim.x + threadIdx.x;  // 0 .. B*N2-1
    const int b   = gid >> 15;          // gid / N2
    const int n2  = gid & (N2 - 1);     // gid % N2

    const float th = thresh[0];

    const size_t base = (size_t)b * T * N2 + n2;
    const f32x2* xp = x   + base;
    f32x2*       op = out + base;

    // Preload all T slices: 16 independent loads issued back-to-back,
    // completing in order -> counted vmcnt waits, full latency overlap.
    f32x2 xt[T];
#pragma unroll
    for (int t = 0; t < T; ++t)
        xt[t] = xp[(size_t)t * N2];

    f32x2 mem = {0.f, 0.f};

#pragma unroll
    for (int t = 0; t < T; ++t) {
        mem.x = mem.x * TAU + xt[t].x;
        mem.y = mem.y * TAU + xt[t].y;

        const bool px = mem.x > th;
        const bool py = mem.y > th;

        f32x2 s;
        s.x = px ? 1.f : 0.f;
        s.y = py ? 1.f : 0.f;

        mem.x = px ? 0.f : mem.x;
        mem.y = py ? 0.f : mem.y;

        __builtin_nontemporal_store(s, &op[(size_t)t * N2]);
    }
}

extern "C" void kernel_launch(void* const* d_in, const int* in_sizes, int n_in,
                              void* d_out, int out_size, void* d_ws, size_t ws_size,
                              hipStream_t stream)
{
    const float* x      = (const float*)d_in[0];
    const float* thresh = (const float*)d_in[1];
    float*       out    = (float*)d_out;

    // total = B*T*N = 33,554,432 ; threads = B*N/2 = total/(16*2) = 1,048,576
    const int total   = in_sizes[0];
    const int threads = total / (16 * 2);
    const int block   = 256;
    const int grid    = threads / block;   // 4096 blocks

    lif_fwd_kernel<<<grid, block, 0, stream>>>(
        (const f32x2*)x, thresh, (f32x2*)out);
}